// Round 6
// baseline (14504.744 us; speedup 1.0000x reference)
//
#include <hip/hip_runtime.h>

typedef unsigned short u16;
typedef short bf16x8 __attribute__((ext_vector_type(8)));
typedef unsigned short ushort8 __attribute__((ext_vector_type(8)));

#define DEVI __device__ __forceinline__

enum { BB = 4, TT = 512, HH = 1024, VV = 32000, H4 = 4096, NWG = 256 };

DEVI u16 f2bf(float f) {
    union { float f; unsigned u; } x; x.f = f;
    unsigned r = x.u + 0x7fff + ((x.u >> 16) & 1);
    return (u16)(r >> 16);
}
DEVI float bf2f(u16 u) {
    union { unsigned u; float f; } x; x.u = ((unsigned)u) << 16;
    return x.f;
}
DEVI float sigm(float x) { return 1.f / (1.f + __expf(-x)); }

// device-scope (cross-XCD, via coherence point) relaxed accesses
DEVI unsigned ald_u32(const unsigned* p) { return __hip_atomic_load(p, __ATOMIC_RELAXED, __HIP_MEMORY_SCOPE_AGENT); }
DEVI void ast_u32(unsigned* p, unsigned v) { __hip_atomic_store(p, v, __ATOMIC_RELAXED, __HIP_MEMORY_SCOPE_AGENT); }

// XCD-scope accesses: sc0 = bypass L1, served by local (shared) L2
DEVI void ld16_sc0(const unsigned* base, int tid, unsigned* v) {
#pragma unroll
    for (int j = 0; j < 16; j++)
        asm volatile("global_load_dword %0, %1, off sc0" : "=v"(v[j]) : "v"(base + j * 256 + tid));
    asm volatile("s_waitcnt vmcnt(0)" ::: "memory");
    __builtin_amdgcn_sched_barrier(0);
}
DEVI void st16_sc0(unsigned* base, int tid, const unsigned* v) {
#pragma unroll
    for (int j = 0; j < 16; j++)
        asm volatile("global_store_dword %0, %1, off sc0" :: "v"(base + j * 256 + tid), "v"(v[j]) : "memory");
}

// consumer staging: poll mailbox (sc0/L2) with timeout, fall back to global (sc1).
// returns true iff mailbox phase succeeded (for persistent fallback).
DEVI bool stage16(const unsigned* mb, const unsigned* gl, unsigned want, u16* dst, int tid, bool use_mb) {
    unsigned v[16];
    bool mb_ok = false;
    if (use_mb) {
        int tries = 0;
        for (;;) {
            ld16_sc0(mb, tid, v);
            bool ok = true;
#pragma unroll
            for (int j = 0; j < 16; j++) ok &= ((v[j] >> 16) == want);
            if (ok) { mb_ok = true; break; }
            if (++tries > 96) break;
            __builtin_amdgcn_s_sleep(1);
        }
    }
    if (!mb_ok) {
        for (;;) {
            bool ok = true;
#pragma unroll
            for (int j = 0; j < 16; j++) v[j] = ald_u32(gl + j * 256 + tid);
#pragma unroll
            for (int j = 0; j < 16; j++) ok &= ((v[j] >> 16) == want);
            if (ok) break;
            __builtin_amdgcn_s_sleep(1);
        }
    }
#pragma unroll
    for (int j = 0; j < 16; j++) dst[j * 256 + tid] = (u16)(v[j] & 0xFFFFu);
    return mb_ok;
}

DEVI bool stage_y0(const unsigned* mbh, const unsigned* mbl, const unsigned* glh, const unsigned* gll,
                   unsigned want, float* dst, int tid, bool use_mb) {
    unsigned vh[16], vl[16];
    bool mb_ok = false;
    if (use_mb) {
        int tries = 0;
        for (;;) {
            ld16_sc0(mbh, tid, vh);
            ld16_sc0(mbl, tid, vl);
            bool ok = true;
#pragma unroll
            for (int j = 0; j < 16; j++) ok &= ((vh[j] >> 16) == want) & ((vl[j] >> 16) == want);
            if (ok) { mb_ok = true; break; }
            if (++tries > 96) break;
            __builtin_amdgcn_s_sleep(1);
        }
    }
    if (!mb_ok) {
        for (;;) {
            bool ok = true;
#pragma unroll
            for (int j = 0; j < 16; j++) { vh[j] = ald_u32(glh + j * 256 + tid); vl[j] = ald_u32(gll + j * 256 + tid); }
#pragma unroll
            for (int j = 0; j < 16; j++) ok &= ((vh[j] >> 16) == want) & ((vl[j] >> 16) == want);
            if (ok) break;
            __builtin_amdgcn_s_sleep(1);
        }
    }
#pragma unroll
    for (int j = 0; j < 16; j++) {
        union { unsigned u; float f; } cv;
        cv.u = ((vh[j] & 0xFFFFu) << 16) | (vl[j] & 0xFFFFu);
        dst[j * 256 + tid] = cv.f;
    }
    return mb_ok;
}

// gateway: poll global (sc1) until the group is complete, republish to mailbox (sc0)
DEVI void gw_pub16(const unsigned* gl, unsigned* mb, unsigned want, int tid) {
    unsigned v[16];
    for (;;) {
        bool ok = true;
#pragma unroll
        for (int j = 0; j < 16; j++) v[j] = ald_u32(gl + j * 256 + tid);
#pragma unroll
        for (int j = 0; j < 16; j++) ok &= ((v[j] >> 16) == want);
        if (ok) break;
        __builtin_amdgcn_s_sleep(1);
    }
    st16_sc0(mb, tid, v);
}

// ---------------- transpose + cast: src [R][C] f32 -> dst [C][R] bf16 ----------------
__global__ void transpose_cast(const float* __restrict__ src, u16* __restrict__ dst, int R, int C) {
    __shared__ float tile[32][33];
    int c0 = blockIdx.x * 32, r0 = blockIdx.y * 32;
    int x = threadIdx.x, y = threadIdx.y;
#pragma unroll
    for (int i = 0; i < 32; i += 8) tile[y + i][x] = src[(size_t)(r0 + y + i) * C + c0 + x];
    __syncthreads();
#pragma unroll
    for (int i = 0; i < 32; i += 8) dst[(size_t)(c0 + y + i) * R + r0 + x] = f2bf(tile[x][y + i]);
}

__global__ void cast_bf16(const float* __restrict__ src, u16* __restrict__ dst, int n) {
    int i = blockIdx.x * 256 + threadIdx.x;
    if (i < n) dst[i] = f2bf(src[i]);
}

__global__ void zero_buf(float* p, int n) {
    int i = blockIdx.x * 256 + threadIdx.x;
    if (i < n) p[i] = 0.f;
}

// ---------------- gather + layernorm (layer 0 input) ----------------
__global__ __launch_bounds__(256) void gather_ln(const int* __restrict__ x, const float* __restrict__ emb,
                                                 const float* __restrict__ g, const float* __restrict__ b,
                                                 float* __restrict__ xe, u16* __restrict__ xn0) {
    int t = blockIdx.x, bb = blockIdx.y;
    int row = x[bb * TT + t];
    const float* e = emb + (size_t)row * HH;
    float v[4]; float s = 0.f, s2 = 0.f;
#pragma unroll
    for (int p = 0; p < 4; p++) { v[p] = e[p * 256 + threadIdx.x]; s += v[p]; s2 += v[p] * v[p]; }
    __shared__ float ls[4], ls2[4];
    for (int off = 32; off; off >>= 1) { s += __shfl_xor(s, off); s2 += __shfl_xor(s2, off); }
    int w = threadIdx.x >> 6, lane = threadIdx.x & 63;
    if (lane == 0) { ls[w] = s; ls2[w] = s2; }
    __syncthreads();
    s = ls[0] + ls[1] + ls[2] + ls[3];
    s2 = ls2[0] + ls2[1] + ls2[2] + ls2[3];
    float mu = s * (1.f / HH);
    float var = s2 * (1.f / HH) - mu * mu;
    float rs = rsqrtf(var + 1e-6f);
    size_t base = ((size_t)t * BB + bb) * HH;
#pragma unroll
    for (int p = 0; p < 4; p++) {
        int j = p * 256 + threadIdx.x;
        xe[base + j] = v[p];
        xn0[base + j] = f2bf((v[p] - mu) * rs * g[j] + b[j]);
    }
}

// ---------------- MFMA GEMM: C[M,N] = A[M,K](bf16) * Bt[N,K](bf16)^T ----------------
template <int MODE>
__global__ __launch_bounds__(256) void gemm_bt(const u16* __restrict__ A, const u16* __restrict__ Bt,
                                               float* __restrict__ Cf, u16* __restrict__ Cb,
                                               const float* __restrict__ bias, int M, int N, int K) {
    __shared__ u16 ldsA[128 * 40];
    __shared__ u16 ldsB[128 * 40];
    typedef float f32x4 __attribute__((ext_vector_type(4)));
    const int tid = threadIdx.x;
    const int m0 = blockIdx.y * 128, n0 = blockIdx.x * 128;
    const int lane = tid & 63, wid = tid >> 6;
    const int wr = wid >> 1, wc = wid & 1;
    const int l15 = lane & 15, lk = (lane >> 4) * 8;
    f32x4 acc[4][4];
#pragma unroll
    for (int a = 0; a < 4; a++)
#pragma unroll
        for (int b = 0; b < 4; b++) { f32x4 z = {0.f, 0.f, 0.f, 0.f}; acc[a][b] = z; }

    const int arow = tid >> 2, acol = (tid & 3) * 8;
    for (int k0 = 0; k0 < K; k0 += 32) {
#pragma unroll
        for (int p = 0; p < 2; p++) {
            int r = arow + p * 64;
            ushort8 va = *(const ushort8*)(A + (size_t)(m0 + r) * K + k0 + acol);
            *(ushort8*)&ldsA[r * 40 + acol] = va;
            ushort8 vb = *(const ushort8*)(Bt + (size_t)(n0 + r) * K + k0 + acol);
            *(ushort8*)&ldsB[r * 40 + acol] = vb;
        }
        __syncthreads();
        bf16x8 af[4], bfr[4];
#pragma unroll
        for (int mi = 0; mi < 4; mi++) af[mi] = *(const bf16x8*)&ldsA[(wr * 64 + mi * 16 + l15) * 40 + lk];
#pragma unroll
        for (int ni = 0; ni < 4; ni++) bfr[ni] = *(const bf16x8*)&ldsB[(wc * 64 + ni * 16 + l15) * 40 + lk];
#pragma unroll
        for (int mi = 0; mi < 4; mi++)
#pragma unroll
            for (int ni = 0; ni < 4; ni++)
                acc[mi][ni] = __builtin_amdgcn_mfma_f32_16x16x32_bf16(af[mi], bfr[ni], acc[mi][ni], 0, 0, 0);
        __syncthreads();
    }
#pragma unroll
    for (int mi = 0; mi < 4; mi++) {
#pragma unroll
        for (int ni = 0; ni < 4; ni++) {
#pragma unroll
            for (int r = 0; r < 4; r++) {
                int gr = m0 + wr * 64 + mi * 16 + (lane >> 4) * 4 + r;
                int gc = n0 + wc * 64 + ni * 16 + l15;
                float v = acc[mi][ni][r];
                if (MODE == 0) {
                    Cf[(size_t)gr * N + gc] = v + bias[gc];
                } else if (MODE == 1) {
                    float u = v + bias[gc];
                    Cb[(size_t)gr * N + gc] = f2bf(u > 0.f ? u : 0.f);
                } else if (MODE == 2) {
                    Cf[(size_t)gr * N + gc] += v;
                } else {
                    int b = gr & 3, t = gr >> 2;
                    Cf[((size_t)b * TT + t) * VV + gc] = v;
                }
            }
        }
    }
}

// ---------------- persistent recurrence kernel (two-level XCD broadcast) ----------------
// G layout (u32): h0[4][4096] | h1[4][4096] | y0hi[4][4096] | y0lo[4][4096]  (65536 u32)
// mbox: 8 mirrors of G, one per XCD (bid%8 heuristic; sc1 fallback if wrong).
__global__ __launch_bounds__(256, 1) void lstm_persist(
    const u16* __restrict__ Wh0, const u16* __restrict__ Wx1, const u16* __restrict__ Wh1,
    const u16* __restrict__ Wo0, const float* __restrict__ pz_all,
    const float* __restrict__ xe, const float* __restrict__ ff0,
    const float* __restrict__ lng, const float* __restrict__ lnb,
    const float* __restrict__ bl, const float* __restrict__ bo,
    float* __restrict__ y0_all, u16* __restrict__ xn1, u16* __restrict__ H1bf,
    unsigned* __restrict__ G, unsigned* __restrict__ mbox) {
    __shared__ u16 lsWh0[4][4][1024];   // 32 KB  [wave][gate][k]
    __shared__ u16 lsWx1[4][4][1024];   // 32 KB
    __shared__ u16 lsWh1[4][4][1024];   // 32 KB
    __shared__ u16 lsWo0[4][1024];      // 8 KB   [wave][k]
    __shared__ u16 sh0[4][1024];        // 8 KB   staged h0 (bf16) [b][k]
    __shared__ u16 sh1[4][1024];        // 8 KB   staged h1 (bf16)
    __shared__ float sy0[4][1024];      // 16 KB  staged y0 (f32)
    __shared__ float cst[2][4][4];      // c-state [layer][wave][b]

    const int w = blockIdx.x;
    const int tid = threadIdx.x;
    const int v = tid >> 6, lane = tid & 63;
    const int iv = w * 4 + v;           // output index owned by this wave
    const int k1 = lane * 8, k2 = 512 + lane * 8;

    unsigned* Gh0 = G;
    unsigned* Gh1 = G + 16384;
    unsigned* Gyh = G + 32768;
    unsigned* Gyl = G + 49152;
    unsigned* MB = mbox + (size_t)(w & 7) * 65536;
    unsigned* Mh0 = MB;
    unsigned* Mh1 = MB + 16384;
    unsigned* Myh = MB + 32768;
    unsigned* Myl = MB + 49152;
    bool use_mb = true;

    // ---- one-time: weights -> LDS (each wave loads its own rows) ----
#pragma unroll
    for (int g = 0; g < 4; g++) {
        size_t row = (size_t)(g * 1024 + iv) * 1024;
        const uint4* s0 = (const uint4*)(Wh0 + row);
        const uint4* s1 = (const uint4*)(Wx1 + row);
        const uint4* s2 = (const uint4*)(Wh1 + row);
        uint4* d0 = (uint4*)&lsWh0[v][g][0];
        uint4* d1 = (uint4*)&lsWx1[v][g][0];
        uint4* d2 = (uint4*)&lsWh1[v][g][0];
        d0[lane * 2] = s0[lane * 2]; d0[lane * 2 + 1] = s0[lane * 2 + 1];
        d1[lane * 2] = s1[lane * 2]; d1[lane * 2 + 1] = s1[lane * 2 + 1];
        d2[lane * 2] = s2[lane * 2]; d2[lane * 2 + 1] = s2[lane * 2 + 1];
    }
    {
        const uint4* s = (const uint4*)(Wo0 + (size_t)iv * 1024);
        uint4* d = (uint4*)&lsWo0[v][0];
        d[lane * 2] = s[lane * 2]; d[lane * 2 + 1] = s[lane * 2 + 1];
    }
    if (tid < 32) ((float*)cst)[tid] = 0.f;

    // ---- one-time: per-lane LN params (layer 1), biases ----
    float lg[16], lbv[16];
    *(float4*)&lg[0]  = *(const float4*)&lng[1024 + k1];
    *(float4*)&lg[4]  = *(const float4*)&lng[1024 + k1 + 4];
    *(float4*)&lg[8]  = *(const float4*)&lng[1024 + k2];
    *(float4*)&lg[12] = *(const float4*)&lng[1024 + k2 + 4];
    *(float4*)&lbv[0]  = *(const float4*)&lnb[1024 + k1];
    *(float4*)&lbv[4]  = *(const float4*)&lnb[1024 + k1 + 4];
    *(float4*)&lbv[8]  = *(const float4*)&lnb[1024 + k2];
    *(float4*)&lbv[12] = *(const float4*)&lnb[1024 + k2 + 4];
    float bl1r[4];
#pragma unroll
    for (int g = 0; g < 4; g++) bl1r[g] = bl[4096 + g * 1024 + iv];
    const float bor = bo[iv];

    __syncthreads();

    for (int s = 0; s < TT + 2; s++) {
        const int t1 = s, t2 = s - 1, t3 = s - 2;
        const bool doP1 = (t1 < TT);
        const bool doP2 = (t2 >= 0 && t2 < TT);
        const bool doP3 = (t3 >= 0 && t3 < TT);
        const bool needH0 = doP1 || doP2;

        // ---- stage cross-wg state into LDS (mailbox sc0; fallback global sc1) ----
        if (needH0) {
            int sl = (t1 + 3) & 3;
            bool r = stage16(Mh0 + sl * 4096, Gh0 + sl * 4096, (unsigned)t1, &sh0[0][0], tid, use_mb);
            use_mb = use_mb && r;
        }
        if (doP3) {
            int sl = (t3 + 3) & 3;
            bool r = stage16(Mh1 + sl * 4096, Gh1 + sl * 4096, (unsigned)t3, &sh1[0][0], tid, use_mb);
            use_mb = use_mb && r;
            int sy = t3 & 3;
            r = stage_y0(Myh + sy * 4096, Myl + sy * 4096, Gyh + sy * 4096, Gyl + sy * 4096,
                         (unsigned)(t3 + 1), &sy0[0][0], tid, use_mb);
            use_mb = use_mb && r;
        }
        float pzv[4] = {0.f, 0.f, 0.f, 0.f}, xev = 0.f, ffv = 0.f;
        if (lane < 4) {
            if (doP1) {
                size_t base = ((size_t)t1 * 4 + lane) * 4096 + iv;
                pzv[0] = pz_all[base];        pzv[1] = pz_all[base + 1024];
                pzv[2] = pz_all[base + 2048]; pzv[3] = pz_all[base + 3072];
            }
            if (doP2) {
                size_t base = ((size_t)t2 * 4 + lane) * 1024 + iv;
                xev = xe[base]; ffv = ff0[base];
            }
        }
        __syncthreads();

        // ---- P3: LN(y0[t3]) + layer-1 gates ----
        if (doP3) {
            float xn[4][16];
#pragma unroll
            for (int b = 0; b < 4; b++) {
                *(float4*)&xn[b][0]  = *(const float4*)&sy0[b][k1];
                *(float4*)&xn[b][4]  = *(const float4*)&sy0[b][k1 + 4];
                *(float4*)&xn[b][8]  = *(const float4*)&sy0[b][k2];
                *(float4*)&xn[b][12] = *(const float4*)&sy0[b][k2 + 4];
                float sm = 0.f, sq = 0.f;
#pragma unroll
                for (int m = 0; m < 16; m++) { sm += xn[b][m]; sq += xn[b][m] * xn[b][m]; }
#pragma unroll
                for (int o = 1; o < 64; o <<= 1) { sm += __shfl_xor(sm, o); sq += __shfl_xor(sq, o); }
                float mu = sm * (1.f / 1024.f);
                float rs = rsqrtf(sq * (1.f / 1024.f) - mu * mu + 1e-6f);
#pragma unroll
                for (int m = 0; m < 16; m++) xn[b][m] = (xn[b][m] - mu) * rs * lg[m] + lbv[m];
            }
            float h1v[4][16];
#pragma unroll
            for (int b = 0; b < 4; b++) {
                ushort8 a = *(const ushort8*)&sh1[b][k1];
                ushort8 c = *(const ushort8*)&sh1[b][k2];
#pragma unroll
                for (int m = 0; m < 8; m++) { h1v[b][m] = bf2f(a[m]); h1v[b][8 + m] = bf2f(c[m]); }
            }
            float za[4][4] = {};
#pragma unroll
            for (int g = 0; g < 4; g++) {
                ushort8 xa = *(const ushort8*)&lsWx1[v][g][k1];
                ushort8 xb = *(const ushort8*)&lsWx1[v][g][k2];
                ushort8 ha = *(const ushort8*)&lsWh1[v][g][k1];
                ushort8 hb = *(const ushort8*)&lsWh1[v][g][k2];
#pragma unroll
                for (int m = 0; m < 8; m++) {
                    float x1 = bf2f(xa[m]), x2 = bf2f(xb[m]);
                    float h1 = bf2f(ha[m]), h2 = bf2f(hb[m]);
#pragma unroll
                    for (int b = 0; b < 4; b++)
                        za[g][b] += x1 * xn[b][m] + x2 * xn[b][8 + m] + h1 * h1v[b][m] + h2 * h1v[b][8 + m];
                }
            }
#pragma unroll
            for (int g = 0; g < 4; g++)
#pragma unroll
                for (int b = 0; b < 4; b++)
#pragma unroll
                    for (int o = 1; o < 64; o <<= 1) za[g][b] += __shfl_xor(za[g][b], o);
            if (lane < 4) {
                int b = lane;
                float ig = sigm(za[0][b] + bl1r[0]);
                float fg = sigm(za[1][b] + bl1r[1]);
                float og = sigm(za[2][b] + bl1r[2]);
                float gg = tanhf(za[3][b] + bl1r[3]);
                float c = fg * cst[1][v][b] + ig * gg;
                cst[1][v][b] = c;
                float h = og * tanhf(c);
                u16 hb16 = f2bf(h);
                ast_u32(&Gh1[(t3 & 3) * 4096 + b * 1024 + iv], ((unsigned)(t3 + 1) << 16) | hb16);
                H1bf[(size_t)t3 * 4096 + b * 1024 + iv] = hb16;   // read by later kernel only
            }
            if (w == 0) {  // write xn1[t3] (bf16) for Phase C; wave v -> row b=v
                ushort8 o1, o2;
#pragma unroll
                for (int m = 0; m < 8; m++) { o1[m] = f2bf(xn[v][m]); o2[m] = f2bf(xn[v][8 + m]); }
                *(ushort8*)&xn1[(size_t)t3 * 4096 + v * 1024 + k1] = o1;
                *(ushort8*)&xn1[(size_t)t3 * 4096 + v * 1024 + k2] = o2;
            }
        }

        // ---- P1 (layer-0 gates) + P2 (y0) share the staged h0 ----
        if (needH0) {
            float h0v[4][16];
#pragma unroll
            for (int b = 0; b < 4; b++) {
                ushort8 a = *(const ushort8*)&sh0[b][k1];
                ushort8 c = *(const ushort8*)&sh0[b][k2];
#pragma unroll
                for (int m = 0; m < 8; m++) { h0v[b][m] = bf2f(a[m]); h0v[b][8 + m] = bf2f(c[m]); }
            }
            if (doP1) {
                float zp[4][4] = {};
#pragma unroll
                for (int g = 0; g < 4; g++) {
                    ushort8 ha = *(const ushort8*)&lsWh0[v][g][k1];
                    ushort8 hb = *(const ushort8*)&lsWh0[v][g][k2];
#pragma unroll
                    for (int m = 0; m < 8; m++) {
                        float w1 = bf2f(ha[m]), w2 = bf2f(hb[m]);
#pragma unroll
                        for (int b = 0; b < 4; b++)
                            zp[g][b] += w1 * h0v[b][m] + w2 * h0v[b][8 + m];
                    }
                }
#pragma unroll
                for (int g = 0; g < 4; g++)
#pragma unroll
                    for (int b = 0; b < 4; b++)
#pragma unroll
                        for (int o = 1; o < 64; o <<= 1) zp[g][b] += __shfl_xor(zp[g][b], o);
                if (lane < 4) {
                    int b = lane;
                    float ig = sigm(zp[0][b] + pzv[0]);
                    float fg = sigm(zp[1][b] + pzv[1]);
                    float og = sigm(zp[2][b] + pzv[2]);
                    float gg = tanhf(zp[3][b] + pzv[3]);
                    float c = fg * cst[0][v][b] + ig * gg;
                    cst[0][v][b] = c;
                    float h = og * tanhf(c);
                    ast_u32(&Gh0[(t1 & 3) * 4096 + b * 1024 + iv], ((unsigned)(t1 + 1) << 16) | f2bf(h));
                }
            }
            if (doP2) {
                float acc[4] = {};
                ushort8 oa = *(const ushort8*)&lsWo0[v][k1];
                ushort8 ob = *(const ushort8*)&lsWo0[v][k2];
#pragma unroll
                for (int m = 0; m < 8; m++) {
                    float w1 = bf2f(oa[m]), w2 = bf2f(ob[m]);
#pragma unroll
                    for (int b = 0; b < 4; b++)
                        acc[b] += w1 * h0v[b][m] + w2 * h0v[b][8 + m];
                }
#pragma unroll
                for (int b = 0; b < 4; b++)
#pragma unroll
                    for (int o = 1; o < 64; o <<= 1) acc[b] += __shfl_xor(acc[b], o);
                if (lane < 4) {
                    int b = lane;
                    float yv = acc[b] + xev + ffv + bor;
                    y0_all[((size_t)t2 * 4 + b) * 1024 + iv] = yv;     // Phase C only
                    union { float f; unsigned u; } cv; cv.f = yv;
                    unsigned tag = (unsigned)(t2 + 1) << 16;
                    ast_u32(&Gyh[(t2 & 3) * 4096 + b * 1024 + iv], tag | (cv.u >> 16));
                    ast_u32(&Gyl[(t2 & 3) * 4096 + b * 1024 + iv], tag | (cv.u & 0xFFFFu));
                }
            }
        }

        // ---- gateway: republish this interval's products to this XCD's mailbox ----
        if (w < 8) {
            if (doP1) gw_pub16(Gh0 + (t1 & 3) * 4096, Mh0 + (t1 & 3) * 4096, (unsigned)(t1 + 1), tid);
            if (doP3) gw_pub16(Gh1 + (t3 & 3) * 4096, Mh1 + (t3 & 3) * 4096, (unsigned)(t3 + 1), tid);
            if (doP2) {
                gw_pub16(Gyh + (t2 & 3) * 4096, Myh + (t2 & 3) * 4096, (unsigned)(t2 + 1), tid);
                gw_pub16(Gyl + (t2 & 3) * 4096, Myl + (t2 & 3) * 4096, (unsigned)(t2 + 1), tid);
            }
        }

        // LDS reuse hazard only: intra-WG barrier (cheap)
        __syncthreads();
    }
}

// ---------------- post-loop elementwise ----------------
__global__ void p1_add(float* __restrict__ y, const float* __restrict__ xe,
                       const float* __restrict__ b2_1, const float* __restrict__ bo_1) {
    int idx = blockIdx.x * 256 + threadIdx.x;
    int j = idx & (HH - 1);
    y[idx] += xe[idx] + b2_1[j] + bo_1[j];
}

__global__ void p2_cast(const float* __restrict__ y, u16* __restrict__ o) {
    int idx = blockIdx.x * 256 + threadIdx.x;
    o[idx] = f2bf(y[idx]);
}

// ---------------- host ----------------
extern "C" void kernel_launch(void* const* d_in, const int* in_sizes, int n_in,
                              void* d_out, int out_size, void* d_ws, size_t ws_size,
                              hipStream_t stream) {
    const int* x = (const int*)d_in[0];
    const float* emb = (const float*)d_in[1];
    const float* ln_g = (const float*)d_in[2];
    const float* ln_b = (const float*)d_in[3];
    const float* Wl = (const float*)d_in[4];
    const float* bl = (const float*)d_in[5];
    const float* Wo = (const float*)d_in[6];
    const float* bo = (const float*)d_in[7];
    const float* W1 = (const float*)d_in[8];
    const float* b1 = (const float*)d_in[9];
    const float* W2 = (const float*)d_in[10];
    const float* b2 = (const float*)d_in[11];
    float* out = (float*)d_out;

    char* wp = (char*)d_ws;
    auto alloc = [&](size_t bytes) { void* p = wp; wp += (bytes + 255) & ~(size_t)255; return p; };
    const size_t MBT = (size_t)TT * BB;  // 2048 rows
    float* xe     = (float*)alloc(MBT * HH * 4);
    float* pre_z0 = (float*)alloc(MBT * H4 * 4);
    float* ff0    = (float*)alloc(MBT * HH * 4);
    float* y0_all = (float*)alloc(MBT * HH * 4);
    u16* xn0      = (u16*)alloc(MBT * HH * 2);
    u16* xn1      = (u16*)alloc(MBT * HH * 2);
    u16* U0       = (u16*)alloc(MBT * H4 * 2);
    u16* U1       = (u16*)alloc(MBT * H4 * 2);
    u16* H1bf     = (u16*)alloc(MBT * HH * 2);
    u16* Y1bf     = (u16*)alloc(MBT * HH * 2);
    // tagged dataflow: global region G (64K u32) + 8 per-XCD mailboxes (64K u32 each)
    unsigned* G    = (unsigned*)alloc(65536 * 4);
    unsigned* mbox = (unsigned*)alloc(8 * 65536 * 4);
    u16* WlxT0 = (u16*)alloc((size_t)H4 * HH * 2);
    u16* WlhT0 = (u16*)alloc((size_t)H4 * HH * 2);
    u16* WlxT1 = (u16*)alloc((size_t)H4 * HH * 2);
    u16* WlhT1 = (u16*)alloc((size_t)H4 * HH * 2);
    u16* Wo0T  = (u16*)alloc((size_t)HH * HH * 2);
    u16* Wo1T  = (u16*)alloc((size_t)HH * HH * 2);
    u16* W10T  = (u16*)alloc((size_t)H4 * HH * 2);
    u16* W11T  = (u16*)alloc((size_t)H4 * HH * 2);
    u16* W20T  = (u16*)alloc((size_t)HH * H4 * 2);
    u16* W21T  = (u16*)alloc((size_t)HH * H4 * 2);
    u16* embB  = (u16*)alloc((size_t)VV * HH * 2);

    dim3 tb(32, 8);
    // Wl: [L][2H][4H]; rows 0..H-1 = x-part, H..2H-1 = h-part
    transpose_cast<<<dim3(128, 32), tb, 0, stream>>>(Wl, WlxT0, HH, H4);
    transpose_cast<<<dim3(128, 32), tb, 0, stream>>>(Wl + 1024 * 4096, WlhT0, HH, H4);
    transpose_cast<<<dim3(128, 32), tb, 0, stream>>>(Wl + 2048 * 4096, WlxT1, HH, H4);
    transpose_cast<<<dim3(128, 32), tb, 0, stream>>>(Wl + 3072 * 4096, WlhT1, HH, H4);
    transpose_cast<<<dim3(32, 32), tb, 0, stream>>>(Wo, Wo0T, HH, HH);
    transpose_cast<<<dim3(32, 32), tb, 0, stream>>>(Wo + 1024 * 1024, Wo1T, HH, HH);
    transpose_cast<<<dim3(128, 32), tb, 0, stream>>>(W1, W10T, HH, H4);
    transpose_cast<<<dim3(128, 32), tb, 0, stream>>>(W1 + 1024 * 4096, W11T, HH, H4);
    transpose_cast<<<dim3(32, 128), tb, 0, stream>>>(W2, W20T, H4, HH);
    transpose_cast<<<dim3(32, 128), tb, 0, stream>>>(W2 + 4096 * 1024, W21T, H4, HH);
    cast_bf16<<<(VV * HH + 255) / 256, 256, 0, stream>>>(emb, embB, VV * HH);
    gather_ln<<<dim3(TT, BB), 256, 0, stream>>>(x, emb, ln_g, ln_b, xe, xn0);

    // Phase A GEMMs (parallel precompute)
    gemm_bt<0><<<dim3(32, 16), 256, 0, stream>>>(xn0, WlxT0, pre_z0, nullptr, bl, 2048, 4096, 1024);
    gemm_bt<1><<<dim3(32, 16), 256, 0, stream>>>(xn0, W10T, nullptr, U0, b1, 2048, 4096, 1024);
    gemm_bt<0><<<dim3(8, 16), 256, 0, stream>>>(U0, W20T, ff0, nullptr, b2, 2048, 1024, 4096);

    // zero G + mailboxes (9 * 64K u32 = 2.25 MB)
    zero_buf<<<2304, 256, 0, stream>>>((float*)G, 9 * 65536);

    // Phase B: persistent recurrence (1 wg/CU, tagged dataflow + XCD gateway broadcast)
    lstm_persist<<<NWG, 256, 0, stream>>>(WlhT0, WlxT1, WlhT1, Wo0T, pre_z0, xe, ff0,
                                          ln_g, ln_b, bl, bo, y0_all, xn1, H1bf, G, mbox);

    // Phase C: deferred layer-1 output + logits
    gemm_bt<1><<<dim3(32, 16), 256, 0, stream>>>(xn1, W11T, nullptr, U1, b1 + 4096, 2048, 4096, 1024);
    p1_add<<<8192, 256, 0, stream>>>(y0_all, xe, b2 + 1024, bo + 1024);
    gemm_bt<2><<<dim3(8, 16), 256, 0, stream>>>(U1, W21T, y0_all, nullptr, nullptr, 2048, 1024, 4096);
    gemm_bt<2><<<dim3(8, 16), 256, 0, stream>>>(H1bf, Wo1T, y0_all, nullptr, nullptr, 2048, 1024, 1024);
    p2_cast<<<8192, 256, 0, stream>>>(y0_all, Y1bf);
    gemm_bt<3><<<dim3(250, 16), 256, 0, stream>>>(Y1bf, embB, out, nullptr, nullptr, 2048, 32000, 1024);
}

// Round 8
// 10162.768 us; speedup vs baseline: 1.4272x; 1.4272x over previous
//
#include <hip/hip_runtime.h>

typedef unsigned short u16;
typedef short bf16x8 __attribute__((ext_vector_type(8)));
typedef unsigned short ushort8 __attribute__((ext_vector_type(8)));
typedef unsigned short us4 __attribute__((ext_vector_type(4)));
typedef unsigned u32x4 __attribute__((ext_vector_type(4)));

#define DEVI __device__ __forceinline__

enum { BB = 4, TT = 512, HH = 1024, VV = 32000, H4 = 4096, NWG = 256 };

DEVI u16 f2bf(float f) {
    union { float f; unsigned u; } x; x.f = f;
    unsigned r = x.u + 0x7fff + ((x.u >> 16) & 1);
    return (u16)(r >> 16);
}
DEVI float bf2f(u16 u) {
    union { unsigned u; float f; } x; x.u = ((unsigned)u) << 16;
    return x.f;
}
DEVI float sigm(float x) { return 1.f / (1.f + __expf(-x)); }

// device-scope (cross-XCD coherent) relaxed accesses
DEVI unsigned ald_u32(const unsigned* p) { return __hip_atomic_load(p, __ATOMIC_RELAXED, __HIP_MEMORY_SCOPE_AGENT); }
DEVI void ast_u32(unsigned* p, unsigned v) { __hip_atomic_store(p, v, __ATOMIC_RELAXED, __HIP_MEMORY_SCOPE_AGENT); }

// wide coherent load: 16B per fabric request, bypass L1+L2 (sc0 sc1)
DEVI void ld4cc(const unsigned* p, u32x4* out) {
    asm volatile("global_load_dwordx4 %0, %1, off sc0 sc1" : "=v"(*out) : "v"(p));
}

// stage one 4096-word tagged region (4 rows x 1024) into LDS rows dst[0..3][tid*4..+3].
// word = (tag<<16)|bf16 payload; poll until all tags == want. dwordx4 polling with
// scalar-atomic fallback after 2048 rounds (deadlock insurance).
DEVI void stage_region(const unsigned* src, unsigned want, u16 (*dst)[1024], int tid) {
    const unsigned* p0 = src + 0 * 1024 + tid * 4;
    const unsigned* p1 = src + 1 * 1024 + tid * 4;
    const unsigned* p2 = src + 2 * 1024 + tid * 4;
    const unsigned* p3 = src + 3 * 1024 + tid * 4;
    u32x4 v0, v1, v2, v3;
    ld4cc(p0, &v0); ld4cc(p1, &v1); ld4cc(p2, &v2); ld4cc(p3, &v3);
    asm volatile("s_waitcnt vmcnt(0)" ::: "memory");
    __builtin_amdgcn_sched_barrier(0);
    int tries = 0;
    for (;;) {
        bool o0 = ((v0[0] >> 16) == want) & ((v0[1] >> 16) == want) & ((v0[2] >> 16) == want) & ((v0[3] >> 16) == want);
        bool o1 = ((v1[0] >> 16) == want) & ((v1[1] >> 16) == want) & ((v1[2] >> 16) == want) & ((v1[3] >> 16) == want);
        bool o2 = ((v2[0] >> 16) == want) & ((v2[1] >> 16) == want) & ((v2[2] >> 16) == want) & ((v2[3] >> 16) == want);
        bool o3 = ((v3[0] >> 16) == want) & ((v3[1] >> 16) == want) & ((v3[2] >> 16) == want) & ((v3[3] >> 16) == want);
        if (o0 & o1 & o2 & o3) break;
        __builtin_amdgcn_s_sleep(2);
        if (++tries > 2048) {   // known-good scalar coherent path
            if (!o0) { v0[0] = ald_u32(p0); v0[1] = ald_u32(p0 + 1); v0[2] = ald_u32(p0 + 2); v0[3] = ald_u32(p0 + 3); }
            if (!o1) { v1[0] = ald_u32(p1); v1[1] = ald_u32(p1 + 1); v1[2] = ald_u32(p1 + 2); v1[3] = ald_u32(p1 + 3); }
            if (!o2) { v2[0] = ald_u32(p2); v2[1] = ald_u32(p2 + 1); v2[2] = ald_u32(p2 + 2); v2[3] = ald_u32(p2 + 3); }
            if (!o3) { v3[0] = ald_u32(p3); v3[1] = ald_u32(p3 + 1); v3[2] = ald_u32(p3 + 2); v3[3] = ald_u32(p3 + 3); }
            continue;
        }
        if (!o0) ld4cc(p0, &v0);
        if (!o1) ld4cc(p1, &v1);
        if (!o2) ld4cc(p2, &v2);
        if (!o3) ld4cc(p3, &v3);
        asm volatile("s_waitcnt vmcnt(0)" ::: "memory");
        __builtin_amdgcn_sched_barrier(0);
    }
    *(us4*)&dst[0][tid * 4] = (us4){(u16)v0[0], (u16)v0[1], (u16)v0[2], (u16)v0[3]};
    *(us4*)&dst[1][tid * 4] = (us4){(u16)v1[0], (u16)v1[1], (u16)v1[2], (u16)v1[3]};
    *(us4*)&dst[2][tid * 4] = (us4){(u16)v2[0], (u16)v2[1], (u16)v2[2], (u16)v2[3]};
    *(us4*)&dst[3][tid * 4] = (us4){(u16)v3[0], (u16)v3[1], (u16)v3[2], (u16)v3[3]};
}

// ---------------- transpose + cast: src [R][C] f32 -> dst [C][R] bf16 ----------------
__global__ void transpose_cast(const float* __restrict__ src, u16* __restrict__ dst, int R, int C) {
    __shared__ float tile[32][33];
    int c0 = blockIdx.x * 32, r0 = blockIdx.y * 32;
    int x = threadIdx.x, y = threadIdx.y;
#pragma unroll
    for (int i = 0; i < 32; i += 8) tile[y + i][x] = src[(size_t)(r0 + y + i) * C + c0 + x];
    __syncthreads();
#pragma unroll
    for (int i = 0; i < 32; i += 8) dst[(size_t)(c0 + y + i) * R + r0 + x] = f2bf(tile[x][y + i]);
}

__global__ void cast_bf16(const float* __restrict__ src, u16* __restrict__ dst, int n) {
    int i = blockIdx.x * 256 + threadIdx.x;
    if (i < n) dst[i] = f2bf(src[i]);
}

__global__ void zero_buf(float* p, int n) {
    int i = blockIdx.x * 256 + threadIdx.x;
    if (i < n) p[i] = 0.f;
}

// ---------------- gather + layernorm (layer 0 input) ----------------
__global__ __launch_bounds__(256) void gather_ln(const int* __restrict__ x, const float* __restrict__ emb,
                                                 const float* __restrict__ g, const float* __restrict__ b,
                                                 float* __restrict__ xe, u16* __restrict__ xn0) {
    int t = blockIdx.x, bb = blockIdx.y;
    int row = x[bb * TT + t];
    const float* e = emb + (size_t)row * HH;
    float v[4]; float s = 0.f, s2 = 0.f;
#pragma unroll
    for (int p = 0; p < 4; p++) { v[p] = e[p * 256 + threadIdx.x]; s += v[p]; s2 += v[p] * v[p]; }
    __shared__ float ls[4], ls2[4];
    for (int off = 32; off; off >>= 1) { s += __shfl_xor(s, off); s2 += __shfl_xor(s2, off); }
    int w = threadIdx.x >> 6, lane = threadIdx.x & 63;
    if (lane == 0) { ls[w] = s; ls2[w] = s2; }
    __syncthreads();
    s = ls[0] + ls[1] + ls[2] + ls[3];
    s2 = ls2[0] + ls2[1] + ls2[2] + ls2[3];
    float mu = s * (1.f / HH);
    float var = s2 * (1.f / HH) - mu * mu;
    float rs = rsqrtf(var + 1e-6f);
    size_t base = ((size_t)t * BB + bb) * HH;
#pragma unroll
    for (int p = 0; p < 4; p++) {
        int j = p * 256 + threadIdx.x;
        xe[base + j] = v[p];
        xn0[base + j] = f2bf((v[p] - mu) * rs * g[j] + b[j]);
    }
}

// ---------------- MFMA GEMM: C[M,N] = A[M,K](bf16) * Bt[N,K](bf16)^T ----------------
template <int MODE>
__global__ __launch_bounds__(256) void gemm_bt(const u16* __restrict__ A, const u16* __restrict__ Bt,
                                               float* __restrict__ Cf, u16* __restrict__ Cb,
                                               const float* __restrict__ bias, int M, int N, int K) {
    __shared__ u16 ldsA[128 * 40];
    __shared__ u16 ldsB[128 * 40];
    typedef float f32x4 __attribute__((ext_vector_type(4)));
    const int tid = threadIdx.x;
    const int m0 = blockIdx.y * 128, n0 = blockIdx.x * 128;
    const int lane = tid & 63, wid = tid >> 6;
    const int wr = wid >> 1, wc = wid & 1;
    const int l15 = lane & 15, lk = (lane >> 4) * 8;
    f32x4 acc[4][4];
#pragma unroll
    for (int a = 0; a < 4; a++)
#pragma unroll
        for (int b = 0; b < 4; b++) { f32x4 z = {0.f, 0.f, 0.f, 0.f}; acc[a][b] = z; }

    const int arow = tid >> 2, acol = (tid & 3) * 8;
    for (int k0 = 0; k0 < K; k0 += 32) {
#pragma unroll
        for (int p = 0; p < 2; p++) {
            int r = arow + p * 64;
            ushort8 va = *(const ushort8*)(A + (size_t)(m0 + r) * K + k0 + acol);
            *(ushort8*)&ldsA[r * 40 + acol] = va;
            ushort8 vb = *(const ushort8*)(Bt + (size_t)(n0 + r) * K + k0 + acol);
            *(ushort8*)&ldsB[r * 40 + acol] = vb;
        }
        __syncthreads();
        bf16x8 af[4], bfr[4];
#pragma unroll
        for (int mi = 0; mi < 4; mi++) af[mi] = *(const bf16x8*)&ldsA[(wr * 64 + mi * 16 + l15) * 40 + lk];
#pragma unroll
        for (int ni = 0; ni < 4; ni++) bfr[ni] = *(const bf16x8*)&ldsB[(wc * 64 + ni * 16 + l15) * 40 + lk];
#pragma unroll
        for (int mi = 0; mi < 4; mi++)
#pragma unroll
            for (int ni = 0; ni < 4; ni++)
                acc[mi][ni] = __builtin_amdgcn_mfma_f32_16x16x32_bf16(af[mi], bfr[ni], acc[mi][ni], 0, 0, 0);
        __syncthreads();
    }
#pragma unroll
    for (int mi = 0; mi < 4; mi++) {
#pragma unroll
        for (int ni = 0; ni < 4; ni++) {
#pragma unroll
            for (int r = 0; r < 4; r++) {
                int gr = m0 + wr * 64 + mi * 16 + (lane >> 4) * 4 + r;
                int gc = n0 + wc * 64 + ni * 16 + l15;
                float v = acc[mi][ni][r];
                if (MODE == 0) {
                    Cf[(size_t)gr * N + gc] = v + bias[gc];
                } else if (MODE == 1) {
                    float u = v + bias[gc];
                    Cb[(size_t)gr * N + gc] = f2bf(u > 0.f ? u : 0.f);
                } else if (MODE == 2) {
                    Cf[(size_t)gr * N + gc] += v;
                } else {
                    int b = gr & 3, t = gr >> 2;
                    Cf[((size_t)b * TT + t) * VV + gc] = v;
                }
            }
        }
    }
}

// ---------------- persistent recurrence kernel (barrier-free tagged dataflow) ----------------
// G layout (u32): h0[4][4096] | h1[4][4096] | y0bf[4][4096]  (49152 u32)
// All cross-WG staging via dwordx4 sc0 sc1 (16B/request) — request-rate is the bottleneck.
__global__ __launch_bounds__(256, 1) void lstm_persist(
    const u16* __restrict__ Wh0, const u16* __restrict__ Wx1, const u16* __restrict__ Wh1,
    const u16* __restrict__ Wo0, const float* __restrict__ pz_all,
    const float* __restrict__ xe, const float* __restrict__ ff0,
    const float* __restrict__ lng, const float* __restrict__ lnb,
    const float* __restrict__ bl, const float* __restrict__ bo,
    float* __restrict__ y0_all, u16* __restrict__ xn1, u16* __restrict__ H1bf,
    unsigned* __restrict__ G) {
    __shared__ u16 lsWh0[4][4][1024];   // 32 KB  [wave][gate][k]
    __shared__ u16 lsWx1[4][4][1024];   // 32 KB
    __shared__ u16 lsWh1[4][4][1024];   // 32 KB
    __shared__ u16 lsWo0[4][1024];      // 8 KB   [wave][k]
    __shared__ u16 sh0[4][1024];        // 8 KB   staged h0 (bf16) [b][k]
    __shared__ u16 sh1[4][1024];        // 8 KB   staged h1 (bf16)
    __shared__ u16 shy[4][1024];        // 8 KB   staged y0 (bf16)
    __shared__ float cst[2][4][4];      // c-state [layer][wave][b]

    const int w = blockIdx.x;
    const int tid = threadIdx.x;
    const int v = tid >> 6, lane = tid & 63;
    const int iv = w * 4 + v;           // output index owned by this wave
    const int k1 = lane * 8, k2 = 512 + lane * 8;

    unsigned* Gh0 = G;
    unsigned* Gh1 = G + 16384;
    unsigned* Gyb = G + 32768;

    // ---- one-time: weights -> LDS (each wave loads its own rows) ----
#pragma unroll
    for (int g = 0; g < 4; g++) {
        size_t row = (size_t)(g * 1024 + iv) * 1024;
        const uint4* s0 = (const uint4*)(Wh0 + row);
        const uint4* s1 = (const uint4*)(Wx1 + row);
        const uint4* s2 = (const uint4*)(Wh1 + row);
        uint4* d0 = (uint4*)&lsWh0[v][g][0];
        uint4* d1 = (uint4*)&lsWx1[v][g][0];
        uint4* d2 = (uint4*)&lsWh1[v][g][0];
        d0[lane * 2] = s0[lane * 2]; d0[lane * 2 + 1] = s0[lane * 2 + 1];
        d1[lane * 2] = s1[lane * 2]; d1[lane * 2 + 1] = s1[lane * 2 + 1];
        d2[lane * 2] = s2[lane * 2]; d2[lane * 2 + 1] = s2[lane * 2 + 1];
    }
    {
        const uint4* s = (const uint4*)(Wo0 + (size_t)iv * 1024);
        uint4* d = (uint4*)&lsWo0[v][0];
        d[lane * 2] = s[lane * 2]; d[lane * 2 + 1] = s[lane * 2 + 1];
    }
    if (tid < 32) ((float*)cst)[tid] = 0.f;

    // ---- one-time: per-lane LN params (layer 1), biases ----
    float lg[16], lbv[16];
    *(float4*)&lg[0]  = *(const float4*)&lng[1024 + k1];
    *(float4*)&lg[4]  = *(const float4*)&lng[1024 + k1 + 4];
    *(float4*)&lg[8]  = *(const float4*)&lng[1024 + k2];
    *(float4*)&lg[12] = *(const float4*)&lng[1024 + k2 + 4];
    *(float4*)&lbv[0]  = *(const float4*)&lnb[1024 + k1];
    *(float4*)&lbv[4]  = *(const float4*)&lnb[1024 + k1 + 4];
    *(float4*)&lbv[8]  = *(const float4*)&lnb[1024 + k2];
    *(float4*)&lbv[12] = *(const float4*)&lnb[1024 + k2 + 4];
    float bl1r[4];
#pragma unroll
    for (int g = 0; g < 4; g++) bl1r[g] = bl[4096 + g * 1024 + iv];
    const float bor = bo[iv];

    __syncthreads();

    for (int s = 0; s < TT + 2; s++) {
        const int t1 = s, t2 = s - 1, t3 = s - 2;
        const bool doP1 = (t1 < TT);
        const bool doP2 = (t2 >= 0 && t2 < TT);
        const bool doP3 = (t3 >= 0 && t3 < TT);
        const bool needH0 = doP1 || doP2;

        // ---- stage cross-wg state into LDS (tag-polling, 16B/request) ----
        if (needH0)
            stage_region(Gh0 + ((t1 + 3) & 3) * 4096, (unsigned)t1, sh0, tid);
        if (doP3) {
            stage_region(Gh1 + ((t3 + 3) & 3) * 4096, (unsigned)t3, sh1, tid);
            stage_region(Gyb + (t3 & 3) * 4096, (unsigned)(t3 + 1), shy, tid);
        }
        float pzv[4] = {0.f, 0.f, 0.f, 0.f}, xev = 0.f, ffv = 0.f;
        if (lane < 4) {
            if (doP1) {
                size_t base = ((size_t)t1 * 4 + lane) * 4096 + iv;
                pzv[0] = pz_all[base];        pzv[1] = pz_all[base + 1024];
                pzv[2] = pz_all[base + 2048]; pzv[3] = pz_all[base + 3072];
            }
            if (doP2) {
                size_t base = ((size_t)t2 * 4 + lane) * 1024 + iv;
                xev = xe[base]; ffv = ff0[base];
            }
        }
        __syncthreads();

        // ---- P3: LN(y0[t3]) + layer-1 gates ----
        if (doP3) {
            float xn[4][16];
#pragma unroll
            for (int b = 0; b < 4; b++) {
                ushort8 ya = *(const ushort8*)&shy[b][k1];
                ushort8 yc = *(const ushort8*)&shy[b][k2];
#pragma unroll
                for (int m = 0; m < 8; m++) { xn[b][m] = bf2f(ya[m]); xn[b][8 + m] = bf2f(yc[m]); }
                float sm = 0.f, sq = 0.f;
#pragma unroll
                for (int m = 0; m < 16; m++) { sm += xn[b][m]; sq += xn[b][m] * xn[b][m]; }
#pragma unroll
                for (int o = 1; o < 64; o <<= 1) { sm += __shfl_xor(sm, o); sq += __shfl_xor(sq, o); }
                float mu = sm * (1.f / 1024.f);
                float rs = rsqrtf(sq * (1.f / 1024.f) - mu * mu + 1e-6f);
#pragma unroll
                for (int m = 0; m < 16; m++) xn[b][m] = (xn[b][m] - mu) * rs * lg[m] + lbv[m];
            }
            float h1v[4][16];
#pragma unroll
            for (int b = 0; b < 4; b++) {
                ushort8 a = *(const ushort8*)&sh1[b][k1];
                ushort8 c = *(const ushort8*)&sh1[b][k2];
#pragma unroll
                for (int m = 0; m < 8; m++) { h1v[b][m] = bf2f(a[m]); h1v[b][8 + m] = bf2f(c[m]); }
            }
            float za[4][4] = {};
#pragma unroll
            for (int g = 0; g < 4; g++) {
                ushort8 xa = *(const ushort8*)&lsWx1[v][g][k1];
                ushort8 xb = *(const ushort8*)&lsWx1[v][g][k2];
                ushort8 ha = *(const ushort8*)&lsWh1[v][g][k1];
                ushort8 hb = *(const ushort8*)&lsWh1[v][g][k2];
#pragma unroll
                for (int m = 0; m < 8; m++) {
                    float x1 = bf2f(xa[m]), x2 = bf2f(xb[m]);
                    float h1 = bf2f(ha[m]), h2 = bf2f(hb[m]);
#pragma unroll
                    for (int b = 0; b < 4; b++)
                        za[g][b] += x1 * xn[b][m] + x2 * xn[b][8 + m] + h1 * h1v[b][m] + h2 * h1v[b][8 + m];
                }
            }
#pragma unroll
            for (int g = 0; g < 4; g++)
#pragma unroll
                for (int b = 0; b < 4; b++)
#pragma unroll
                    for (int o = 1; o < 64; o <<= 1) za[g][b] += __shfl_xor(za[g][b], o);
            if (lane < 4) {
                int b = lane;
                float ig = sigm(za[0][b] + bl1r[0]);
                float fg = sigm(za[1][b] + bl1r[1]);
                float og = sigm(za[2][b] + bl1r[2]);
                float gg = tanhf(za[3][b] + bl1r[3]);
                float c = fg * cst[1][v][b] + ig * gg;
                cst[1][v][b] = c;
                float h = og * tanhf(c);
                u16 hb16 = f2bf(h);
                ast_u32(&Gh1[(t3 & 3) * 4096 + b * 1024 + iv], ((unsigned)(t3 + 1) << 16) | hb16);
                H1bf[(size_t)t3 * 4096 + b * 1024 + iv] = hb16;   // read by later kernel only
            }
            if (w == 0) {  // write xn1[t3] (bf16) for Phase C; wave v -> row b=v
                ushort8 o1, o2;
#pragma unroll
                for (int m = 0; m < 8; m++) { o1[m] = f2bf(xn[v][m]); o2[m] = f2bf(xn[v][8 + m]); }
                *(ushort8*)&xn1[(size_t)t3 * 4096 + v * 1024 + k1] = o1;
                *(ushort8*)&xn1[(size_t)t3 * 4096 + v * 1024 + k2] = o2;
            }
        }

        // ---- P1 (layer-0 gates) + P2 (y0) share the staged h0 ----
        if (needH0) {
            float h0v[4][16];
#pragma unroll
            for (int b = 0; b < 4; b++) {
                ushort8 a = *(const ushort8*)&sh0[b][k1];
                ushort8 c = *(const ushort8*)&sh0[b][k2];
#pragma unroll
                for (int m = 0; m < 8; m++) { h0v[b][m] = bf2f(a[m]); h0v[b][8 + m] = bf2f(c[m]); }
            }
            if (doP1) {
                float zp[4][4] = {};
#pragma unroll
                for (int g = 0; g < 4; g++) {
                    ushort8 ha = *(const ushort8*)&lsWh0[v][g][k1];
                    ushort8 hb = *(const ushort8*)&lsWh0[v][g][k2];
#pragma unroll
                    for (int m = 0; m < 8; m++) {
                        float w1 = bf2f(ha[m]), w2 = bf2f(hb[m]);
#pragma unroll
                        for (int b = 0; b < 4; b++)
                            zp[g][b] += w1 * h0v[b][m] + w2 * h0v[b][8 + m];
                    }
                }
#pragma unroll
                for (int g = 0; g < 4; g++)
#pragma unroll
                    for (int b = 0; b < 4; b++)
#pragma unroll
                        for (int o = 1; o < 64; o <<= 1) zp[g][b] += __shfl_xor(zp[g][b], o);
                if (lane < 4) {
                    int b = lane;
                    float ig = sigm(zp[0][b] + pzv[0]);
                    float fg = sigm(zp[1][b] + pzv[1]);
                    float og = sigm(zp[2][b] + pzv[2]);
                    float gg = tanhf(zp[3][b] + pzv[3]);
                    float c = fg * cst[0][v][b] + ig * gg;
                    cst[0][v][b] = c;
                    float h = og * tanhf(c);
                    ast_u32(&Gh0[(t1 & 3) * 4096 + b * 1024 + iv], ((unsigned)(t1 + 1) << 16) | f2bf(h));
                }
            }
            if (doP2) {
                float acc[4] = {};
                ushort8 oa = *(const ushort8*)&lsWo0[v][k1];
                ushort8 ob = *(const ushort8*)&lsWo0[v][k2];
#pragma unroll
                for (int m = 0; m < 8; m++) {
                    float w1 = bf2f(oa[m]), w2 = bf2f(ob[m]);
#pragma unroll
                    for (int b = 0; b < 4; b++)
                        acc[b] += w1 * h0v[b][m] + w2 * h0v[b][8 + m];
                }
#pragma unroll
                for (int b = 0; b < 4; b++)
#pragma unroll
                    for (int o = 1; o < 64; o <<= 1) acc[b] += __shfl_xor(acc[b], o);
                if (lane < 4) {
                    int b = lane;
                    float yv = acc[b] + xev + ffv + bor;
                    y0_all[((size_t)t2 * 4 + b) * 1024 + iv] = yv;     // full f32 for Phase C
                    ast_u32(&Gyb[(t2 & 3) * 4096 + b * 1024 + iv],
                            ((unsigned)(t2 + 1) << 16) | f2bf(yv));
                }
            }
        }

        // LDS reuse hazard only: intra-WG barrier (cheap)
        __syncthreads();
    }
}

// ---------------- post-loop elementwise ----------------
__global__ void p1_add(float* __restrict__ y, const float* __restrict__ xe,
                       const float* __restrict__ b2_1, const float* __restrict__ bo_1) {
    int idx = blockIdx.x * 256 + threadIdx.x;
    int j = idx & (HH - 1);
    y[idx] += xe[idx] + b2_1[j] + bo_1[j];
}

__global__ void p2_cast(const float* __restrict__ y, u16* __restrict__ o) {
    int idx = blockIdx.x * 256 + threadIdx.x;
    o[idx] = f2bf(y[idx]);
}

// ---------------- host ----------------
extern "C" void kernel_launch(void* const* d_in, const int* in_sizes, int n_in,
                              void* d_out, int out_size, void* d_ws, size_t ws_size,
                              hipStream_t stream) {
    const int* x = (const int*)d_in[0];
    const float* emb = (const float*)d_in[1];
    const float* ln_g = (const float*)d_in[2];
    const float* ln_b = (const float*)d_in[3];
    const float* Wl = (const float*)d_in[4];
    const float* bl = (const float*)d_in[5];
    const float* Wo = (const float*)d_in[6];
    const float* bo = (const float*)d_in[7];
    const float* W1 = (const float*)d_in[8];
    const float* b1 = (const float*)d_in[9];
    const float* W2 = (const float*)d_in[10];
    const float* b2 = (const float*)d_in[11];
    float* out = (float*)d_out;

    char* wp = (char*)d_ws;
    auto alloc = [&](size_t bytes) { void* p = wp; wp += (bytes + 255) & ~(size_t)255; return p; };
    const size_t MBT = (size_t)TT * BB;  // 2048 rows
    float* xe     = (float*)alloc(MBT * HH * 4);
    float* pre_z0 = (float*)alloc(MBT * H4 * 4);
    float* ff0    = (float*)alloc(MBT * HH * 4);
    float* y0_all = (float*)alloc(MBT * HH * 4);
    u16* xn0      = (u16*)alloc(MBT * HH * 2);
    u16* xn1      = (u16*)alloc(MBT * HH * 2);
    u16* U0       = (u16*)alloc(MBT * H4 * 2);
    u16* U1       = (u16*)alloc(MBT * H4 * 2);
    u16* H1bf     = (u16*)alloc(MBT * HH * 2);
    u16* Y1bf     = (u16*)alloc(MBT * HH * 2);
    // tagged dataflow region G: h0 | h1 | y0bf, each 4 slots x 4096 u32 = 49152 u32
    unsigned* G   = (unsigned*)alloc(49152 * 4);
    u16* WlxT0 = (u16*)alloc((size_t)H4 * HH * 2);
    u16* WlhT0 = (u16*)alloc((size_t)H4 * HH * 2);
    u16* WlxT1 = (u16*)alloc((size_t)H4 * HH * 2);
    u16* WlhT1 = (u16*)alloc((size_t)H4 * HH * 2);
    u16* Wo0T  = (u16*)alloc((size_t)HH * HH * 2);
    u16* Wo1T  = (u16*)alloc((size_t)HH * HH * 2);
    u16* W10T  = (u16*)alloc((size_t)H4 * HH * 2);
    u16* W11T  = (u16*)alloc((size_t)H4 * HH * 2);
    u16* W20T  = (u16*)alloc((size_t)HH * H4 * 2);
    u16* W21T  = (u16*)alloc((size_t)HH * H4 * 2);
    u16* embB  = (u16*)alloc((size_t)VV * HH * 2);

    dim3 tb(32, 8);
    // Wl: [L][2H][4H]; rows 0..H-1 = x-part, H..2H-1 = h-part
    transpose_cast<<<dim3(128, 32), tb, 0, stream>>>(Wl, WlxT0, HH, H4);
    transpose_cast<<<dim3(128, 32), tb, 0, stream>>>(Wl + 1024 * 4096, WlhT0, HH, H4);
    transpose_cast<<<dim3(128, 32), tb, 0, stream>>>(Wl + 2048 * 4096, WlxT1, HH, H4);
    transpose_cast<<<dim3(128, 32), tb, 0, stream>>>(Wl + 3072 * 4096, WlhT1, HH, H4);
    transpose_cast<<<dim3(32, 32), tb, 0, stream>>>(Wo, Wo0T, HH, HH);
    transpose_cast<<<dim3(32, 32), tb, 0, stream>>>(Wo + 1024 * 1024, Wo1T, HH, HH);
    transpose_cast<<<dim3(128, 32), tb, 0, stream>>>(W1, W10T, HH, H4);
    transpose_cast<<<dim3(128, 32), tb, 0, stream>>>(W1 + 1024 * 4096, W11T, HH, H4);
    transpose_cast<<<dim3(32, 128), tb, 0, stream>>>(W2, W20T, H4, HH);
    transpose_cast<<<dim3(32, 128), tb, 0, stream>>>(W2 + 4096 * 1024, W21T, H4, HH);
    cast_bf16<<<(VV * HH + 255) / 256, 256, 0, stream>>>(emb, embB, VV * HH);
    gather_ln<<<dim3(TT, BB), 256, 0, stream>>>(x, emb, ln_g, ln_b, xe, xn0);

    // Phase A GEMMs (parallel precompute)
    gemm_bt<0><<<dim3(32, 16), 256, 0, stream>>>(xn0, WlxT0, pre_z0, nullptr, bl, 2048, 4096, 1024);
    gemm_bt<1><<<dim3(32, 16), 256, 0, stream>>>(xn0, W10T, nullptr, U0, b1, 2048, 4096, 1024);
    gemm_bt<0><<<dim3(8, 16), 256, 0, stream>>>(U0, W20T, ff0, nullptr, b2, 2048, 1024, 4096);

    // zero tagged region (49152 u32)
    zero_buf<<<192, 256, 0, stream>>>((float*)G, 49152);

    // Phase B: persistent recurrence (1 wg/CU, barrier-free tagged dataflow, wide loads)
    lstm_persist<<<NWG, 256, 0, stream>>>(WlhT0, WlxT1, WlhT1, Wo0T, pre_z0, xe, ff0,
                                          ln_g, ln_b, bl, bo, y0_all, xn1, H1bf, G);

    // Phase C: deferred layer-1 output + logits
    gemm_bt<1><<<dim3(32, 16), 256, 0, stream>>>(xn1, W11T, nullptr, U1, b1 + 4096, 2048, 4096, 1024);
    p1_add<<<8192, 256, 0, stream>>>(y0_all, xe, b2 + 1024, bo + 1024);
    gemm_bt<2><<<dim3(8, 16), 256, 0, stream>>>(U1, W21T, y0_all, nullptr, nullptr, 2048, 1024, 4096);
    gemm_bt<2><<<dim3(8, 16), 256, 0, stream>>>(H1bf, Wo1T, y0_all, nullptr, nullptr, 2048, 1024, 1024);
    p2_cast<<<8192, 256, 0, stream>>>(y0_all, Y1bf);
    gemm_bt<3><<<dim3(250, 16), 256, 0, stream>>>(Y1bf, embB, out, nullptr, nullptr, 2048, 32000, 1024);
}